// Round 3
// baseline (119.268 us; speedup 1.0000x reference)
//
#include <hip/hip_runtime.h>
#include <stdint.h>
#include <math.h>

// Problem constants (B=8192 rows, D=512 features)
#define Bn 8192
#define Dn 512
#define EPSN 1e-12f
#define EPSP 1e-6f
#define MARG 0.3f
#define QS 256.0f
#define ISQ (2.0f / 65536.0f)

// R20 = R18 with K2 rebuilt on the 256^2 8-phase schedule (T3+T4+T5):
//   - 256x256 tile, 8 waves (2j x 4i), per-wave out 128x64, acc 8x4 int4.
//   - 4-slot LDS ring (slot = kt&3, 4 x 16 KB per matrix, 128 KB, 1 blk/CU):
//     provably race-free — stage(kt+2) issues during tile kt, its slot's last
//     reader finished at tile kt-2 (two closing barriers earlier).
//   - counted vmcnt(4) once per K-tile (end of phase 3), never 0 in steady
//     state; vmcnt(0) only entering the last tile. Loads span barriers.
//   - per phase: {2 ds_read A (+4 B at p0) | 1 gload_lds -> s_barrier ->
//     lgkmcnt(0)+sched_barrier(0) [rule 18] -> setprio(1) 8 MFMA setprio(0)
//     -> barrier}. 4 phases per K-tile.
//   - staging slot-XOR swizzle byte-identical to R11..R18 (BANK_CONFLICT=0),
//     generalized to 256 rows; epilogue = R18's in-lane max remapped to the
//     8-wave layout (32 in-lane j's, 2 u32 shuffle steps, LDS wr-combine,
//     one u32 atomicMax per (block,i)).
// R18 post-mortem: epilogue fix confirmed (K2 77->48.5us, MfmaUtil 17->28,
// prediction matched). Remaining limit = 2-barrier vmcnt(0) drain structure
// (known ~36% ceiling, m233); counted-vmcnt alone is null there (m131/m139),
// so this jumps straight to the verified 256^2+8phase quadrant.
// Ledger: occupancy lever exhausted (R2/R5/R6), B-out-of-LDS loses (R4/R7),
// fp8 mfma_scale spills (R9), i8 2xK wins (R11), packed partials kill write
// amplification (R14/R15), algebraic neg^2 kills gather (R16), single-address
// atomics +100us (R5), ticket+fence +20us (R10), cooperative launch no-ops
// under graph capture (R12), epilogue-VALU fixed by C^T+u32 keys (R18).

#define TKB 64                 // k bytes per K-tile
#define NKT (Dn / TKB)         // 8 K-tiles

typedef int   int4v __attribute__((ext_vector_type(4)));
typedef float f32x4 __attribute__((ext_vector_type(4)));

// async global->LDS, 16B per lane; LDS dest is wave-uniform base + lane*16
__device__ __forceinline__ void async16(const void* g, void* l) {
    __builtin_amdgcn_global_load_lds(
        (const __attribute__((address_space(1))) void*)g,
        (__attribute__((address_space(3))) void*)l,
        16, 0, 0);
}

// monotonic float->u32 key: key(a) > key(b) iff a > b (finite floats).
// Any finite score's key is nonzero, so 0 is the atomicMax identity.
__device__ __forceinline__ unsigned key32(float s) {
    union { float f; unsigned u; } c; c.f = s;
    return (c.u & 0x80000000u) ? ~c.u : (c.u | 0x80000000u);
}
__device__ __forceinline__ float unkey32(unsigned k) {
    union { unsigned u; float f; } c;
    c.u = (k & 0x80000000u) ? (k ^ 0x80000000u) : ~k;
    return c.f;
}

// ---------------------------------------------------------------------------
// K1: one wave per row pair (a_i, p_i): L2-normalize both -> i8 rows (x256,
// RNE, clamp +-127), column term c[j] = -sp2[j] + 2*eps*sp[j], rowconst[i] =
// pos2 - sa2 - 2*eps*sa - D*eps^2 + MARGIN (exact fp32), and rowmax[i] = 0.
// ---------------------------------------------------------------------------
__global__ __launch_bounds__(256) void k_normalize(
    const float* __restrict__ x,
    uint8_t* __restrict__ a_i8, uint8_t* __restrict__ p_i8,
    float* __restrict__ cterm, float* __restrict__ rowconst,
    unsigned* __restrict__ rowmax)
{
    const int wave = threadIdx.x >> 6;
    const int lane = threadIdx.x & 63;
    const int i = blockIdx.x * 4 + wave;   // 0..8191

    const float* srcA = x + (size_t)i * (2 * Dn) + lane * 8;
    const float* srcP = srcA + Dn;
    float4 a0 = ((const float4*)srcA)[0];
    float4 a1 = ((const float4*)srcA)[1];
    float4 p0 = ((const float4*)srcP)[0];
    float4 p1 = ((const float4*)srcP)[1];
    float va[8] = {a0.x, a0.y, a0.z, a0.w, a1.x, a1.y, a1.z, a1.w};
    float vp[8] = {p0.x, p0.y, p0.z, p0.w, p1.x, p1.y, p1.z, p1.w};

    float ssa = 0.f, ssp = 0.f;
#pragma unroll
    for (int j = 0; j < 8; ++j) { ssa += va[j] * va[j]; ssp += vp[j] * vp[j]; }
#pragma unroll
    for (int m = 1; m < 64; m <<= 1) {
        ssa += __shfl_xor(ssa, m);
        ssp += __shfl_xor(ssp, m);
    }
    const float sa = 1.0f / fmaxf(sqrtf(ssa), EPSN);
    const float sp = 1.0f / fmaxf(sqrtf(ssp), EPSN);

    float oa[8], op[8];
    float s1p = 0.f, s2p = 0.f, s1a = 0.f, s2a = 0.f, pos = 0.f;
#pragma unroll
    for (int j = 0; j < 8; ++j) {
        oa[j] = va[j] * sa;
        op[j] = vp[j] * sp;
        s1p += op[j]; s2p += op[j] * op[j];
        s1a += oa[j]; s2a += oa[j] * oa[j];
        const float u = oa[j] - op[j] + EPSP;
        pos += u * u;
    }

    uint64_t pka = 0, pkp = 0;
#pragma unroll
    for (int j = 0; j < 8; ++j) {
        int qa = (int)rintf(oa[j] * QS);
        int qp = (int)rintf(op[j] * QS);
        qa = qa > 127 ? 127 : (qa < -127 ? -127 : qa);
        qp = qp > 127 ? 127 : (qp < -127 ? -127 : qp);
        pka |= (uint64_t)(uint8_t)qa << (8 * j);
        pkp |= (uint64_t)(uint8_t)qp << (8 * j);
    }
    *(uint64_t*)(a_i8 + (size_t)i * Dn + lane * 8) = pka;
    *(uint64_t*)(p_i8 + (size_t)i * Dn + lane * 8) = pkp;

#pragma unroll
    for (int m = 1; m < 64; m <<= 1) {
        s1p += __shfl_xor(s1p, m);
        s2p += __shfl_xor(s2p, m);
        s1a += __shfl_xor(s1a, m);
        s2a += __shfl_xor(s2a, m);
        pos += __shfl_xor(pos, m);
    }
    if (lane == 0) {
        cterm[i] = -s2p + 2.0f * EPSP * s1p;
        rowconst[i] = pos - s2a - 2.0f * EPSP * s1a
                      - (float)Dn * EPSP * EPSP + MARG;
        rowmax[i] = 0u;              // atomicMax identity (poisoned otherwise)
    }
}

// ---------------------------------------------------------------------------
// K2: i8 MFMA GEMM, 256^2 tile, 8-phase counted-vmcnt schedule, swapped
// operands (acc = C^T: j in-lane, i across lanes), fused per-i max.
// ---------------------------------------------------------------------------
__global__ __launch_bounds__(512, 2) void k_gemm_argmax(
    const uint8_t* __restrict__ a_i8, const uint8_t* __restrict__ p_i8,
    const float* __restrict__ cterm,
    unsigned* __restrict__ rowmax)
{
    __shared__ __align__(16) uint8_t As[4][256 * TKB];   // 64 KB, p rows (j)
    __shared__ __align__(16) uint8_t Bs[4][256 * TKB];   // 64 KB, a rows (i)
    __shared__ unsigned smx[2][256];                     // wr-half combine

    const int t = threadIdx.x;          // 0..511
    const int wave = t >> 6;            // 0..7
    const int lane = t & 63;
    const int q = lane >> 4;            // 0..3  (k-chunk; C/D row = q*4+v)
    const int m16 = lane & 15;          // 0..15 (C/D col)
    const int wr = wave >> 2;           // j half (0..1)
    const int wc = wave & 3;            // i quarter (0..3)
    const int j0 = blockIdx.y * 256;    // p-row base
    const int i0 = blockIdx.x * 256;    // a-row base (rowmax index)

    // ---- staging: per K-tile = 4 insts/thread (A half0, A half1, B h0, B h1)
    // thread t covers chunk t of the half: row = half*128 + (t>>2), global
    // k-slot g = (t&3) ^ ((t>>3)&3)  (slot-XOR swizzle, BANK_CONFLICT=0).
    const int rr = t >> 2;                               // 0..127
    const int gg = ((t & 3) ^ ((t >> 3) & 3)) * 16;      // byte slot in k-tile
    const uint8_t* gA0 = p_i8 + (size_t)(j0 + rr) * Dn + gg;
    const uint8_t* gA1 = p_i8 + (size_t)(j0 + 128 + rr) * Dn + gg;
    const uint8_t* gB0 = a_i8 + (size_t)(i0 + rr) * Dn + gg;
    const uint8_t* gB1 = a_i8 + (size_t)(i0 + 128 + rr) * Dn + gg;
    const int ldsOff = wave * 1024;     // + HW lane*16; halves at +8192

    // ---- fragment read bases: slot = q ^ ((m16>>1)&3) (matches storage XOR)
    const int sl = (q ^ ((m16 >> 1) & 3)) * 16;
    const int aOff = (wr * 128 + m16) * TKB + sl;        // + mt*1024
    const int bOff = (wc * 64 + m16) * TKB + sl;         // + nt*1024

    auto stage1 = [&](int slot, int kb, int h) {
        switch (h) {
        case 0: async16(gA0 + kb, &As[slot][ldsOff]);        break;
        case 1: async16(gA1 + kb, &As[slot][8192 + ldsOff]); break;
        case 2: async16(gB0 + kb, &Bs[slot][ldsOff]);        break;
        case 3: async16(gB1 + kb, &Bs[slot][8192 + ldsOff]); break;
        }
    };

    int4v acc[8][4];
#pragma unroll
    for (int a = 0; a < 8; ++a)
#pragma unroll
        for (int b = 0; b < 4; ++b) acc[a][b] = (int4v){0, 0, 0, 0};

    // prologue: stage tiles 0 and 1 (FIFO), wait tile 0 landed (4 in flight)
#pragma unroll
    for (int h = 0; h < 4; ++h) stage1(0, 0, h);
#pragma unroll
    for (int h = 0; h < 4; ++h) stage1(1, TKB, h);
    asm volatile("s_waitcnt vmcnt(4)" ::: "memory");
    __builtin_amdgcn_s_barrier();

#pragma unroll
    for (int kt = 0; kt < NKT; ++kt) {
        const int slot = kt & 3;
        const uint8_t* pa = &As[slot][aOff];
        const uint8_t* pb = &Bs[slot][bOff];
        int4v bf[4];
#pragma unroll
        for (int p = 0; p < 4; ++p) {
            // issue this phase's LDS reads (slot stable for the whole tile)
            int4v af0 = *(const int4v*)(pa + (2 * p) * 1024);
            int4v af1 = *(const int4v*)(pa + (2 * p + 1) * 1024);
            if (p == 0) {
#pragma unroll
                for (int nt = 0; nt < 4; ++nt)
                    bf[nt] = *(const int4v*)(pb + nt * 1024);
            }
            // issue 1 staging inst for tile kt+2 (slot free since tile kt-2)
            if (kt + 2 < NKT) stage1((kt + 2) & 3, (kt + 2) * TKB, p);

            __builtin_amdgcn_s_barrier();
            asm volatile("s_waitcnt lgkmcnt(0)" ::: "memory");
            __builtin_amdgcn_sched_barrier(0);   // rule 18: pin MFMA after wait
            __builtin_amdgcn_s_setprio(1);
#pragma unroll
            for (int nt = 0; nt < 4; ++nt)
                acc[2 * p][nt] = __builtin_amdgcn_mfma_i32_16x16x64_i8(
                    af0, bf[nt], acc[2 * p][nt], 0, 0, 0);
#pragma unroll
            for (int nt = 0; nt < 4; ++nt)
                acc[2 * p + 1][nt] = __builtin_amdgcn_mfma_i32_16x16x64_i8(
                    af1, bf[nt], acc[2 * p + 1][nt], 0, 0, 0);
            __builtin_amdgcn_s_setprio(0);
            if (p == 3) {
                // counted drain: next tile's 4 loads must land; keep the
                // following tile's 4 in flight. Never 0 until the last edge.
                if (kt + 2 < NKT)
                    asm volatile("s_waitcnt vmcnt(4)" ::: "memory");
                else if (kt + 2 == NKT)
                    asm volatile("s_waitcnt vmcnt(0)" ::: "memory");
            }
            __builtin_amdgcn_s_barrier();
        }
    }

    // ---- epilogue: acc[mt][nt][v] = idot(j, i) with
    //   j = j0 + wr*128 + mt*16 + q*4 + v   (32 in-lane candidates per nt)
    //   i = i0 + wc*64  + nt*16 + m16
    f32x4 cj[8];
#pragma unroll
    for (int mt = 0; mt < 8; ++mt)   // broadcast loads, L2-resident 32 KB
        cj[mt] = *(const f32x4*)(cterm + j0 + wr * 128 + mt * 16 + q * 4);

    unsigned kv[4];
    const bool diag = (i0 == j0);    // 32 of 1024 blocks
    if (!diag) {
#pragma unroll
        for (int nt = 0; nt < 4; ++nt) {
            float mx = -3.4e38f;
#pragma unroll
            for (int mt = 0; mt < 8; ++mt)
#pragma unroll
                for (int v = 0; v < 4; ++v)
                    mx = fmaxf(mx, ISQ * (float)acc[mt][nt][v] + cj[mt][v]);
            kv[nt] = key32(mx);
        }
    } else {
#pragma unroll
        for (int nt = 0; nt < 4; ++nt) {
            // j==i  <=>  mt*16+v == dtarget (at most one of the 32)
            const int dtarget = wc * 64 + nt * 16 + m16 - wr * 128 - q * 4;
            float mx = -3.4e38f;
#pragma unroll
            for (int mt = 0; mt < 8; ++mt)
#pragma unroll
                for (int v = 0; v < 4; ++v) {
                    const float sc = ISQ * (float)acc[mt][nt][v] + cj[mt][v];
                    mx = (mt * 16 + v == dtarget) ? mx : fmaxf(mx, sc);
                }
            kv[nt] = key32(mx);
        }
    }

    // combine the 4 q-groups (same i, different j): masks 16, 32
#pragma unroll
    for (int nt = 0; nt < 4; ++nt) {
#pragma unroll
        for (int msk = 16; msk < 64; msk <<= 1) {
            const unsigned o = (unsigned)__shfl_xor((int)kv[nt], msk);
            kv[nt] = o > kv[nt] ? o : kv[nt];
        }
    }
    if (lane < 16) {   // q==0 lanes hold the reduced keys
#pragma unroll
        for (int nt = 0; nt < 4; ++nt)
            smx[wr][wc * 64 + nt * 16 + m16] = kv[nt];
    }
    __syncthreads();
    if (t < 256) {
        const unsigned k0 = smx[0][t];
        const unsigned k1 = smx[1][t];
        // distributed per-row max: 32 blocks contend per address (order-
        // independent -> deterministic), 8192 addresses total.
        atomicMax(&rowmax[i0 + t], k0 > k1 ? k0 : k1);
    }
}

// ---------------------------------------------------------------------------
// K3: single block - loss = mean(relu(rowconst[i] + score_max[i])).
// Reads 64 KB; deterministic fixed-order sums.
// ---------------------------------------------------------------------------
__global__ __launch_bounds__(1024) void k_final(
    const unsigned* __restrict__ rowmax,
    const float* __restrict__ rowconst,
    float* __restrict__ out)
{
    __shared__ float smf[16];
    float s = 0.f;
    for (int k = threadIdx.x; k < Bn; k += 1024)
        s += fmaxf(rowconst[k] + unkey32(rowmax[k]), 0.f);
#pragma unroll
    for (int msk = 1; msk < 64; msk <<= 1) s += __shfl_xor(s, msk);
    if ((threadIdx.x & 63) == 0) smf[threadIdx.x >> 6] = s;
    __syncthreads();
    if (threadIdx.x == 0) {
        float tot = 0.f;
#pragma unroll
        for (int w = 0; w < 16; ++w) tot += smf[w];
        out[0] = tot * (1.0f / Bn);
    }
}

extern "C" void kernel_launch(void* const* d_in, const int* in_sizes, int n_in,
                              void* d_out, int out_size, void* d_ws, size_t ws_size,
                              hipStream_t stream)
{
    const float* x = (const float*)d_in[0];
    char* ws = (char*)d_ws;
    // workspace layout (bytes):
    uint8_t*  a_i8     = (uint8_t*)(ws + 0);         // 4 MB
    uint8_t*  p_i8     = (uint8_t*)(ws + 4194304);   // 4 MB
    float*    cterm    = (float*)(ws + 8388608);     // 32 KB
    float*    rowconst = (float*)(ws + 8421376);     // 32 KB
    unsigned* rowmax   = (unsigned*)(ws + 8454144);  // 32 KB (total ~8.5 MB)
    float*    out      = (float*)d_out;

    k_normalize<<<2048, 256, 0, stream>>>(x, a_i8, p_i8, cterm, rowconst, rowmax);
    k_gemm_argmax<<<dim3(Bn / 256, Bn / 256), 512, 0, stream>>>(
        a_i8, p_i8, cterm, rowmax);
    k_final<<<1, 1024, 0, stream>>>(rowmax, rowconst, out);
}

// Round 4
// 115.045 us; speedup vs baseline: 1.0367x; 1.0367x over previous
//
#include <hip/hip_runtime.h>
#include <stdint.h>
#include <math.h>

// Problem constants (B=8192 rows, D=512 features)
#define Bn 8192
#define Dn 512
#define EPSN 1e-12f
#define EPSP 1e-6f
#define MARG 0.3f
#define QS 256.0f
#define ISQ (2.0f / 65536.0f)

// R21 = R20 with the K-loop re-phased: ONE barrier per K-tile, 32-MFMA
// cluster (was: 2 barriers per 8-MFMA phase, 4 phases/tile).
// R20 post-mortem: 8-phase port was NEUTRAL (47.4 vs 48.5us, MfmaUtil 27).
// Measured phase = 889 cy; MFMA need = 326 cy (2 waves/SIMD x 8 x 20.4);
// ~560 cy/phase fixed cost (2 barriers + lgkm + setprio + issue) amortized
// over HALF the MFMAs of the verified bf16 template (i8 K=64 = 1 MFMA per
// frag pair vs bf16's 2). Fix: amortize over 32 MFMAs -> 8 barriers total.
// Cross-wave LDS/MFMA overlap is preserved: lgkmcnt is per-wave, so waves
// enter the MFMA cluster staggered as the LDS pipe drains their reads.
// Kept from R20 (passed, absmax 0.0): 256^2 tile, 8 waves (2j x 4i), 4-slot
// LDS ring (race-free: stage(kt+2) writes a slot last read at tile kt-2,
// >=2 barriers earlier), counted vmcnt(4) (never 0 until the last edge),
// slot-XOR staging (BANK_CONFLICT=0 across 8 rounds), C^T epilogue with u32
// float keys + distributed atomicMax.
// Ledger: occupancy lever exhausted (R2/R5/R6), B-out-of-LDS loses (R4/R7),
// fp8 mfma_scale spills (R9), i8 2xK wins (R11), packed partials kill write
// amplification (R14/R15), algebraic neg^2 kills gather (R16), single-address
// atomics +100us (R5), ticket+fence +20us (R10), cooperative launch no-ops
// under graph capture (R12), epilogue-VALU fixed by C^T+u32 keys (R18),
// thin phases (8 MFMA/barrier-pair) NEUTRAL vs 2-barrier loop (R20).

#define TKB 64                 // k bytes per K-tile
#define NKT (Dn / TKB)         // 8 K-tiles

typedef int   int4v __attribute__((ext_vector_type(4)));
typedef float f32x4 __attribute__((ext_vector_type(4)));

// async global->LDS, 16B per lane; LDS dest is wave-uniform base + lane*16
__device__ __forceinline__ void async16(const void* g, void* l) {
    __builtin_amdgcn_global_load_lds(
        (const __attribute__((address_space(1))) void*)g,
        (__attribute__((address_space(3))) void*)l,
        16, 0, 0);
}

// monotonic float->u32 key: key(a) > key(b) iff a > b (finite floats).
// Any finite score's key is nonzero, so 0 is the atomicMax identity.
__device__ __forceinline__ unsigned key32(float s) {
    union { float f; unsigned u; } c; c.f = s;
    return (c.u & 0x80000000u) ? ~c.u : (c.u | 0x80000000u);
}
__device__ __forceinline__ float unkey32(unsigned k) {
    union { unsigned u; float f; } c;
    c.u = (k & 0x80000000u) ? (k ^ 0x80000000u) : ~k;
    return c.f;
}

// ---------------------------------------------------------------------------
// K1: one wave per row pair (a_i, p_i): L2-normalize both -> i8 rows (x256,
// RNE, clamp +-127), column term c[j] = -sp2[j] + 2*eps*sp[j], rowconst[i] =
// pos2 - sa2 - 2*eps*sa - D*eps^2 + MARGIN (exact fp32), and rowmax[i] = 0.
// ---------------------------------------------------------------------------
__global__ __launch_bounds__(256) void k_normalize(
    const float* __restrict__ x,
    uint8_t* __restrict__ a_i8, uint8_t* __restrict__ p_i8,
    float* __restrict__ cterm, float* __restrict__ rowconst,
    unsigned* __restrict__ rowmax)
{
    const int wave = threadIdx.x >> 6;
    const int lane = threadIdx.x & 63;
    const int i = blockIdx.x * 4 + wave;   // 0..8191

    const float* srcA = x + (size_t)i * (2 * Dn) + lane * 8;
    const float* srcP = srcA + Dn;
    float4 a0 = ((const float4*)srcA)[0];
    float4 a1 = ((const float4*)srcA)[1];
    float4 p0 = ((const float4*)srcP)[0];
    float4 p1 = ((const float4*)srcP)[1];
    float va[8] = {a0.x, a0.y, a0.z, a0.w, a1.x, a1.y, a1.z, a1.w};
    float vp[8] = {p0.x, p0.y, p0.z, p0.w, p1.x, p1.y, p1.z, p1.w};

    float ssa = 0.f, ssp = 0.f;
#pragma unroll
    for (int j = 0; j < 8; ++j) { ssa += va[j] * va[j]; ssp += vp[j] * vp[j]; }
#pragma unroll
    for (int m = 1; m < 64; m <<= 1) {
        ssa += __shfl_xor(ssa, m);
        ssp += __shfl_xor(ssp, m);
    }
    const float sa = 1.0f / fmaxf(sqrtf(ssa), EPSN);
    const float sp = 1.0f / fmaxf(sqrtf(ssp), EPSN);

    float oa[8], op[8];
    float s1p = 0.f, s2p = 0.f, s1a = 0.f, s2a = 0.f, pos = 0.f;
#pragma unroll
    for (int j = 0; j < 8; ++j) {
        oa[j] = va[j] * sa;
        op[j] = vp[j] * sp;
        s1p += op[j]; s2p += op[j] * op[j];
        s1a += oa[j]; s2a += oa[j] * oa[j];
        const float u = oa[j] - op[j] + EPSP;
        pos += u * u;
    }

    uint64_t pka = 0, pkp = 0;
#pragma unroll
    for (int j = 0; j < 8; ++j) {
        int qa = (int)rintf(oa[j] * QS);
        int qp = (int)rintf(op[j] * QS);
        qa = qa > 127 ? 127 : (qa < -127 ? -127 : qa);
        qp = qp > 127 ? 127 : (qp < -127 ? -127 : qp);
        pka |= (uint64_t)(uint8_t)qa << (8 * j);
        pkp |= (uint64_t)(uint8_t)qp << (8 * j);
    }
    *(uint64_t*)(a_i8 + (size_t)i * Dn + lane * 8) = pka;
    *(uint64_t*)(p_i8 + (size_t)i * Dn + lane * 8) = pkp;

#pragma unroll
    for (int m = 1; m < 64; m <<= 1) {
        s1p += __shfl_xor(s1p, m);
        s2p += __shfl_xor(s2p, m);
        s1a += __shfl_xor(s1a, m);
        s2a += __shfl_xor(s2a, m);
        pos += __shfl_xor(pos, m);
    }
    if (lane == 0) {
        cterm[i] = -s2p + 2.0f * EPSP * s1p;
        rowconst[i] = pos - s2a - 2.0f * EPSP * s1a
                      - (float)Dn * EPSP * EPSP + MARG;
        rowmax[i] = 0u;              // atomicMax identity (poisoned otherwise)
    }
}

// ---------------------------------------------------------------------------
// K2: i8 MFMA GEMM, 256^2 tile, 1-barrier-per-K-tile fat-phase schedule,
// counted vmcnt, 4-slot LDS ring, swapped operands (acc = C^T), fused max.
// ---------------------------------------------------------------------------
__global__ __launch_bounds__(512, 2) void k_gemm_argmax(
    const uint8_t* __restrict__ a_i8, const uint8_t* __restrict__ p_i8,
    const float* __restrict__ cterm,
    unsigned* __restrict__ rowmax)
{
    __shared__ __align__(16) uint8_t As[4][256 * TKB];   // 64 KB, p rows (j)
    __shared__ __align__(16) uint8_t Bs[4][256 * TKB];   // 64 KB, a rows (i)
    __shared__ unsigned smx[2][256];                     // wr-half combine

    const int t = threadIdx.x;          // 0..511
    const int wave = t >> 6;            // 0..7
    const int lane = t & 63;
    const int q = lane >> 4;            // 0..3  (k-chunk; C/D row = q*4+v)
    const int m16 = lane & 15;          // 0..15 (C/D col)
    const int wr = wave >> 2;           // j half (0..1)
    const int wc = wave & 3;            // i quarter (0..3)
    const int j0 = blockIdx.y * 256;    // p-row base
    const int i0 = blockIdx.x * 256;    // a-row base (rowmax index)

    // ---- staging: per K-tile = 4 insts/thread (A half0, A half1, B h0, B h1)
    // thread t covers chunk t of the half: row = half*128 + (t>>2), global
    // k-slot g = (t&3) ^ ((t>>3)&3)  (slot-XOR swizzle, BANK_CONFLICT=0).
    const int rr = t >> 2;                               // 0..127
    const int gg = ((t & 3) ^ ((t >> 3) & 3)) * 16;      // byte slot in k-tile
    const uint8_t* gA0 = p_i8 + (size_t)(j0 + rr) * Dn + gg;
    const uint8_t* gA1 = p_i8 + (size_t)(j0 + 128 + rr) * Dn + gg;
    const uint8_t* gB0 = a_i8 + (size_t)(i0 + rr) * Dn + gg;
    const uint8_t* gB1 = a_i8 + (size_t)(i0 + 128 + rr) * Dn + gg;
    const int ldsOff = wave * 1024;     // + HW lane*16; halves at +8192

    // ---- fragment read bases: slot = q ^ ((m16>>1)&3) (matches storage XOR)
    const int sl = (q ^ ((m16 >> 1) & 3)) * 16;
    const int aOff = (wr * 128 + m16) * TKB + sl;        // + mt*1024
    const int bOff = (wc * 64 + m16) * TKB + sl;         // + nt*1024

    auto stage1 = [&](int slot, int kb, int h) {
        switch (h) {
        case 0: async16(gA0 + kb, &As[slot][ldsOff]);        break;
        case 1: async16(gA1 + kb, &As[slot][8192 + ldsOff]); break;
        case 2: async16(gB0 + kb, &Bs[slot][ldsOff]);        break;
        case 3: async16(gB1 + kb, &Bs[slot][8192 + ldsOff]); break;
        }
    };

    int4v acc[8][4];
#pragma unroll
    for (int a = 0; a < 8; ++a)
#pragma unroll
        for (int b = 0; b < 4; ++b) acc[a][b] = (int4v){0, 0, 0, 0};

    // prologue: stage tiles 0 and 1 (FIFO), wait tile 0 landed (4 in flight)
#pragma unroll
    for (int h = 0; h < 4; ++h) stage1(0, 0, h);
#pragma unroll
    for (int h = 0; h < 4; ++h) stage1(1, TKB, h);
    asm volatile("s_waitcnt vmcnt(4)" ::: "memory");
    __builtin_amdgcn_s_barrier();

#pragma unroll
    for (int kt = 0; kt < NKT; ++kt) {
        const int slot = kt & 3;
        const uint8_t* pa = &As[slot][aOff];
        const uint8_t* pb = &Bs[slot][bOff];

        // issue ALL of this tile's LDS reads (12 x ds_read_b128) ...
        int4v af[8], bf[4];
#pragma unroll
        for (int mt = 0; mt < 8; ++mt)
            af[mt] = *(const int4v*)(pa + mt * 1024);
#pragma unroll
        for (int nt = 0; nt < 4; ++nt)
            bf[nt] = *(const int4v*)(pb + nt * 1024);
        // ... and this tile's 4 staging insts for tile kt+2 (slot free since
        // tile kt-2, two closing barriers ago)
        if (kt + 2 < NKT) {
#pragma unroll
            for (int h = 0; h < 4; ++h) stage1((kt + 2) & 3, (kt + 2) * TKB, h);
        }

        // per-wave wait: waves enter the MFMA cluster staggered as the LDS
        // pipe drains their reads -> cross-wave LDS/MFMA overlap.
        asm volatile("s_waitcnt lgkmcnt(0)" ::: "memory");
        __builtin_amdgcn_sched_barrier(0);   // rule 18: pin MFMA after wait
        __builtin_amdgcn_s_setprio(1);
#pragma unroll
        for (int mt = 0; mt < 8; ++mt)
#pragma unroll
            for (int nt = 0; nt < 4; ++nt)
                acc[mt][nt] = __builtin_amdgcn_mfma_i32_16x16x64_i8(
                    af[mt], bf[nt], acc[mt][nt], 0, 0, 0);
        __builtin_amdgcn_s_setprio(0);

        // counted drain: next tile's 4 loads must land; keep the following
        // tile's 4 in flight. Never 0 until the last edge.
        if (kt + 2 < NKT)
            asm volatile("s_waitcnt vmcnt(4)" ::: "memory");
        else if (kt + 2 == NKT)
            asm volatile("s_waitcnt vmcnt(0)" ::: "memory");
        if (kt + 1 < NKT) __builtin_amdgcn_s_barrier();
    }

    // ---- epilogue: acc[mt][nt][v] = idot(j, i) with
    //   j = j0 + wr*128 + mt*16 + q*4 + v   (32 in-lane candidates per nt)
    //   i = i0 + wc*64  + nt*16 + m16
    f32x4 cj[8];
#pragma unroll
    for (int mt = 0; mt < 8; ++mt)   // broadcast loads, L2-resident 32 KB
        cj[mt] = *(const f32x4*)(cterm + j0 + wr * 128 + mt * 16 + q * 4);

    unsigned kv[4];
    const bool diag = (i0 == j0);    // 32 of 1024 blocks
    if (!diag) {
#pragma unroll
        for (int nt = 0; nt < 4; ++nt) {
            float mx = -3.4e38f;
#pragma unroll
            for (int mt = 0; mt < 8; ++mt)
#pragma unroll
                for (int v = 0; v < 4; ++v)
                    mx = fmaxf(mx, ISQ * (float)acc[mt][nt][v] + cj[mt][v]);
            kv[nt] = key32(mx);
        }
    } else {
#pragma unroll
        for (int nt = 0; nt < 4; ++nt) {
            // j==i  <=>  mt*16+v == dtarget (at most one of the 32)
            const int dtarget = wc * 64 + nt * 16 + m16 - wr * 128 - q * 4;
            float mx = -3.4e38f;
#pragma unroll
            for (int mt = 0; mt < 8; ++mt)
#pragma unroll
                for (int v = 0; v < 4; ++v) {
                    const float sc = ISQ * (float)acc[mt][nt][v] + cj[mt][v];
                    mx = (mt * 16 + v == dtarget) ? mx : fmaxf(mx, sc);
                }
            kv[nt] = key32(mx);
        }
    }

    // combine the 4 q-groups (same i, different j): masks 16, 32
#pragma unroll
    for (int nt = 0; nt < 4; ++nt) {
#pragma unroll
        for (int msk = 16; msk < 64; msk <<= 1) {
            const unsigned o = (unsigned)__shfl_xor((int)kv[nt], msk);
            kv[nt] = o > kv[nt] ? o : kv[nt];
        }
    }
    if (lane < 16) {   // q==0 lanes hold the reduced keys
#pragma unroll
        for (int nt = 0; nt < 4; ++nt)
            smx[wr][wc * 64 + nt * 16 + m16] = kv[nt];
    }
    __syncthreads();
    if (t < 256) {
        const unsigned k0 = smx[0][t];
        const unsigned k1 = smx[1][t];
        // distributed per-row max: 32 blocks contend per address (order-
        // independent -> deterministic), 8192 addresses total.
        atomicMax(&rowmax[i0 + t], k0 > k1 ? k0 : k1);
    }
}

// ---------------------------------------------------------------------------
// K3: single block - loss = mean(relu(rowconst[i] + score_max[i])).
// Reads 64 KB; deterministic fixed-order sums.
// ---------------------------------------------------------------------------
__global__ __launch_bounds__(1024) void k_final(
    const unsigned* __restrict__ rowmax,
    const float* __restrict__ rowconst,
    float* __restrict__ out)
{
    __shared__ float smf[16];
    float s = 0.f;
    for (int k = threadIdx.x; k < Bn; k += 1024)
        s += fmaxf(rowconst[k] + unkey32(rowmax[k]), 0.f);
#pragma unroll
    for (int msk = 1; msk < 64; msk <<= 1) s += __shfl_xor(s, msk);
    if ((threadIdx.x & 63) == 0) smf[threadIdx.x >> 6] = s;
    __syncthreads();
    if (threadIdx.x == 0) {
        float tot = 0.f;
#pragma unroll
        for (int w = 0; w < 16; ++w) tot += smf[w];
        out[0] = tot * (1.0f / Bn);
    }
}

extern "C" void kernel_launch(void* const* d_in, const int* in_sizes, int n_in,
                              void* d_out, int out_size, void* d_ws, size_t ws_size,
                              hipStream_t stream)
{
    const float* x = (const float*)d_in[0];
    char* ws = (char*)d_ws;
    // workspace layout (bytes):
    uint8_t*  a_i8     = (uint8_t*)(ws + 0);         // 4 MB
    uint8_t*  p_i8     = (uint8_t*)(ws + 4194304);   // 4 MB
    float*    cterm    = (float*)(ws + 8388608);     // 32 KB
    float*    rowconst = (float*)(ws + 8421376);     // 32 KB
    unsigned* rowmax   = (unsigned*)(ws + 8454144);  // 32 KB (total ~8.5 MB)
    float*    out      = (float*)d_out;

    k_normalize<<<2048, 256, 0, stream>>>(x, a_i8, p_i8, cterm, rowconst, rowmax);
    k_gemm_argmax<<<dim3(Bn / 256, Bn / 256), 512, 0, stream>>>(
        a_i8, p_i8, cterm, rowmax);
    k_final<<<1, 1024, 0, stream>>>(rowmax, rowconst, out);
}

// Round 5
// 113.130 us; speedup vs baseline: 1.0542x; 1.0169x over previous
//
#include <hip/hip_runtime.h>
#include <stdint.h>
#include <math.h>

// Problem constants (B=8192 rows, D=512 features)
#define Bn 8192
#define Dn 512
#define EPSN 1e-12f
#define EPSP 1e-6f
#define MARG 0.3f
#define QS 256.0f
#define ISQ (2.0f / 65536.0f)

// R22 = R21 with the per-tile lgkmcnt(0) monolith split into COUNTED lgkm
// waits: issue all 12 ds_read_b128 in pinned-order groups, then
// lgkm(6)->MFMA{af0,af1}, lgkm(4)->{af2,af3}, lgkm(2)->{af4,af5},
// lgkm(0)->{af6,af7}. DS completes in-order per wave, so each wait releases
// exactly the fragments its MFMA group needs while later reads stream.
// R21 post-mortem: fat phases NEUTRAL (47.4->45.3us) - barrier count was
// never dominant. Real serialization: lgkmcnt(0) forces LDS burst (1155cy)
// and MFMA cluster (1306cy) to ALTERNATE per tile (measured 3.4k cy/tile).
// This round overlaps them within the wave. Staging moved after the lgkm(0)
// wait so vmem ops never alias the counted-lgkm ledger.
// Also learned: a 256MB harness workspace-poison fill (~45us @ 74% HBM peak)
// sits inside dur_us - fixed floor, not controllable; K2 is the only lever.
// Kept from R21 (passed, absmax 0.0): 256^2 tile, 8 waves (2j x 4i), 4-slot
// LDS ring (stage(kt+2) writes a slot last read at tile kt-2), counted
// vmcnt(4) protocol, slot-XOR staging (BANK_CONFLICT=0 across 9 rounds),
// C^T epilogue with u32 float keys + distributed atomicMax.
// Ledger: occupancy lever exhausted (R2/R5/R6), B-out-of-LDS loses (R4/R7),
// fp8 mfma_scale spills (R9), i8 2xK wins (R11), packed partials kill write
// amplification (R14/R15), algebraic neg^2 kills gather (R16), single-address
// atomics +100us (R5), ticket+fence +20us (R10), cooperative launch no-ops
// under graph capture (R12), epilogue-VALU fixed by C^T+u32 keys (R18),
// thin phases NEUTRAL (R20), fat phases NEUTRAL (R21): sync granularity
// exhausted - intra-wave LDS/MFMA overlap is the remaining K2 lever.

#define TKB 64                 // k bytes per K-tile
#define NKT (Dn / TKB)         // 8 K-tiles

typedef int   int4v __attribute__((ext_vector_type(4)));
typedef float f32x4 __attribute__((ext_vector_type(4)));

// async global->LDS, 16B per lane; LDS dest is wave-uniform base + lane*16
__device__ __forceinline__ void async16(const void* g, void* l) {
    __builtin_amdgcn_global_load_lds(
        (const __attribute__((address_space(1))) void*)g,
        (__attribute__((address_space(3))) void*)l,
        16, 0, 0);
}

// monotonic float->u32 key: key(a) > key(b) iff a > b (finite floats).
// Any finite score's key is nonzero, so 0 is the atomicMax identity.
__device__ __forceinline__ unsigned key32(float s) {
    union { float f; unsigned u; } c; c.f = s;
    return (c.u & 0x80000000u) ? ~c.u : (c.u | 0x80000000u);
}
__device__ __forceinline__ float unkey32(unsigned k) {
    union { unsigned u; float f; } c;
    c.u = (k & 0x80000000u) ? (k ^ 0x80000000u) : ~k;
    return c.f;
}

// ---------------------------------------------------------------------------
// K1: one wave per row pair (a_i, p_i): L2-normalize both -> i8 rows (x256,
// RNE, clamp +-127), column term c[j] = -sp2[j] + 2*eps*sp[j], rowconst[i] =
// pos2 - sa2 - 2*eps*sa - D*eps^2 + MARGIN (exact fp32), and rowmax[i] = 0.
// ---------------------------------------------------------------------------
__global__ __launch_bounds__(256) void k_normalize(
    const float* __restrict__ x,
    uint8_t* __restrict__ a_i8, uint8_t* __restrict__ p_i8,
    float* __restrict__ cterm, float* __restrict__ rowconst,
    unsigned* __restrict__ rowmax)
{
    const int wave = threadIdx.x >> 6;
    const int lane = threadIdx.x & 63;
    const int i = blockIdx.x * 4 + wave;   // 0..8191

    const float* srcA = x + (size_t)i * (2 * Dn) + lane * 8;
    const float* srcP = srcA + Dn;
    float4 a0 = ((const float4*)srcA)[0];
    float4 a1 = ((const float4*)srcA)[1];
    float4 p0 = ((const float4*)srcP)[0];
    float4 p1 = ((const float4*)srcP)[1];
    float va[8] = {a0.x, a0.y, a0.z, a0.w, a1.x, a1.y, a1.z, a1.w};
    float vp[8] = {p0.x, p0.y, p0.z, p0.w, p1.x, p1.y, p1.z, p1.w};

    float ssa = 0.f, ssp = 0.f;
#pragma unroll
    for (int j = 0; j < 8; ++j) { ssa += va[j] * va[j]; ssp += vp[j] * vp[j]; }
#pragma unroll
    for (int m = 1; m < 64; m <<= 1) {
        ssa += __shfl_xor(ssa, m);
        ssp += __shfl_xor(ssp, m);
    }
    const float sa = 1.0f / fmaxf(sqrtf(ssa), EPSN);
    const float sp = 1.0f / fmaxf(sqrtf(ssp), EPSN);

    float oa[8], op[8];
    float s1p = 0.f, s2p = 0.f, s1a = 0.f, s2a = 0.f, pos = 0.f;
#pragma unroll
    for (int j = 0; j < 8; ++j) {
        oa[j] = va[j] * sa;
        op[j] = vp[j] * sp;
        s1p += op[j]; s2p += op[j] * op[j];
        s1a += oa[j]; s2a += oa[j] * oa[j];
        const float u = oa[j] - op[j] + EPSP;
        pos += u * u;
    }

    uint64_t pka = 0, pkp = 0;
#pragma unroll
    for (int j = 0; j < 8; ++j) {
        int qa = (int)rintf(oa[j] * QS);
        int qp = (int)rintf(op[j] * QS);
        qa = qa > 127 ? 127 : (qa < -127 ? -127 : qa);
        qp = qp > 127 ? 127 : (qp < -127 ? -127 : qp);
        pka |= (uint64_t)(uint8_t)qa << (8 * j);
        pkp |= (uint64_t)(uint8_t)qp << (8 * j);
    }
    *(uint64_t*)(a_i8 + (size_t)i * Dn + lane * 8) = pka;
    *(uint64_t*)(p_i8 + (size_t)i * Dn + lane * 8) = pkp;

#pragma unroll
    for (int m = 1; m < 64; m <<= 1) {
        s1p += __shfl_xor(s1p, m);
        s2p += __shfl_xor(s2p, m);
        s1a += __shfl_xor(s1a, m);
        s2a += __shfl_xor(s2a, m);
        pos += __shfl_xor(pos, m);
    }
    if (lane == 0) {
        cterm[i] = -s2p + 2.0f * EPSP * s1p;
        rowconst[i] = pos - s2a - 2.0f * EPSP * s1a
                      - (float)Dn * EPSP * EPSP + MARG;
        rowmax[i] = 0u;              // atomicMax identity (poisoned otherwise)
    }
}

// ---------------------------------------------------------------------------
// K2: i8 MFMA GEMM, 256^2 tile, counted-lgkm intra-tile pipeline, counted
// vmcnt, 4-slot LDS ring, swapped operands (acc = C^T), fused per-i max.
// ---------------------------------------------------------------------------
__global__ __launch_bounds__(512, 2) void k_gemm_argmax(
    const uint8_t* __restrict__ a_i8, const uint8_t* __restrict__ p_i8,
    const float* __restrict__ cterm,
    unsigned* __restrict__ rowmax)
{
    __shared__ __align__(16) uint8_t As[4][256 * TKB];   // 64 KB, p rows (j)
    __shared__ __align__(16) uint8_t Bs[4][256 * TKB];   // 64 KB, a rows (i)
    __shared__ unsigned smx[2][256];                     // wr-half combine

    const int t = threadIdx.x;          // 0..511
    const int wave = t >> 6;            // 0..7
    const int lane = t & 63;
    const int q = lane >> 4;            // 0..3  (k-chunk; C/D row = q*4+v)
    const int m16 = lane & 15;          // 0..15 (C/D col)
    const int wr = wave >> 2;           // j half (0..1)
    const int wc = wave & 3;            // i quarter (0..3)
    const int j0 = blockIdx.y * 256;    // p-row base
    const int i0 = blockIdx.x * 256;    // a-row base (rowmax index)

    // ---- staging: per K-tile = 4 insts/thread (A half0, A half1, B h0, B h1)
    // thread t covers chunk t of the half: row = half*128 + (t>>2), global
    // k-slot g = (t&3) ^ ((t>>3)&3)  (slot-XOR swizzle, BANK_CONFLICT=0).
    const int rr = t >> 2;                               // 0..127
    const int gg = ((t & 3) ^ ((t >> 3) & 3)) * 16;      // byte slot in k-tile
    const uint8_t* gA0 = p_i8 + (size_t)(j0 + rr) * Dn + gg;
    const uint8_t* gA1 = p_i8 + (size_t)(j0 + 128 + rr) * Dn + gg;
    const uint8_t* gB0 = a_i8 + (size_t)(i0 + rr) * Dn + gg;
    const uint8_t* gB1 = a_i8 + (size_t)(i0 + 128 + rr) * Dn + gg;
    const int ldsOff = wave * 1024;     // + HW lane*16; halves at +8192

    // ---- fragment read bases: slot = q ^ ((m16>>1)&3) (matches storage XOR)
    const int sl = (q ^ ((m16 >> 1) & 3)) * 16;
    const int aOff = (wr * 128 + m16) * TKB + sl;        // + mt*1024
    const int bOff = (wc * 64 + m16) * TKB + sl;         // + nt*1024

    auto stage1 = [&](int slot, int kb, int h) {
        switch (h) {
        case 0: async16(gA0 + kb, &As[slot][ldsOff]);        break;
        case 1: async16(gA1 + kb, &As[slot][8192 + ldsOff]); break;
        case 2: async16(gB0 + kb, &Bs[slot][ldsOff]);        break;
        case 3: async16(gB1 + kb, &Bs[slot][8192 + ldsOff]); break;
        }
    };

    int4v acc[8][4];
#pragma unroll
    for (int a = 0; a < 8; ++a)
#pragma unroll
        for (int b = 0; b < 4; ++b) acc[a][b] = (int4v){0, 0, 0, 0};

    // prologue: stage tiles 0 and 1 (FIFO), wait tile 0 landed (4 in flight)
#pragma unroll
    for (int h = 0; h < 4; ++h) stage1(0, 0, h);
#pragma unroll
    for (int h = 0; h < 4; ++h) stage1(1, TKB, h);
    asm volatile("s_waitcnt vmcnt(4)" ::: "memory");
    __builtin_amdgcn_s_barrier();

#pragma unroll
    for (int kt = 0; kt < NKT; ++kt) {
        const int slot = kt & 3;
        const uint8_t* pa = &As[slot][aOff];
        const uint8_t* pb = &Bs[slot][bOff];

        int4v af[8], bf[4];
        // ---- issue all 12 ds_read_b128 in PINNED order (DS completes
        // in-order per wave -> counted lgkm waits release exact subsets).
        bf[0] = *(const int4v*)(pb + 0 * 1024);
        bf[1] = *(const int4v*)(pb + 1 * 1024);
        bf[2] = *(const int4v*)(pb + 2 * 1024);
        bf[3] = *(const int4v*)(pb + 3 * 1024);
        af[0] = *(const int4v*)(pa + 0 * 1024);
        af[1] = *(const int4v*)(pa + 1 * 1024);
        __builtin_amdgcn_sched_barrier(0);   // pin: group1 = oldest 6
        af[2] = *(const int4v*)(pa + 2 * 1024);
        af[3] = *(const int4v*)(pa + 3 * 1024);
        __builtin_amdgcn_sched_barrier(0);
        af[4] = *(const int4v*)(pa + 4 * 1024);
        af[5] = *(const int4v*)(pa + 5 * 1024);
        __builtin_amdgcn_sched_barrier(0);
        af[6] = *(const int4v*)(pa + 6 * 1024);
        af[7] = *(const int4v*)(pa + 7 * 1024);
        __builtin_amdgcn_sched_barrier(0);

        // ---- pipelined MFMA: each counted wait releases one 8-MFMA group
        // while the remaining ds_reads stream underneath.
        asm volatile("s_waitcnt lgkmcnt(6)" ::: "memory");
        __builtin_amdgcn_sched_barrier(0);   // rule 18
        __builtin_amdgcn_s_setprio(1);
#pragma unroll
        for (int nt = 0; nt < 4; ++nt)
            acc[0][nt] = __builtin_amdgcn_mfma_i32_16x16x64_i8(
                af[0], bf[nt], acc[0][nt], 0, 0, 0);
#pragma unroll
        for (int nt = 0; nt < 4; ++nt)
            acc[1][nt] = __builtin_amdgcn_mfma_i32_16x16x64_i8(
                af[1], bf[nt], acc[1][nt], 0, 0, 0);

        asm volatile("s_waitcnt lgkmcnt(4)" ::: "memory");
        __builtin_amdgcn_sched_barrier(0);
#pragma unroll
        for (int nt = 0; nt < 4; ++nt)
            acc[2][nt] = __builtin_amdgcn_mfma_i32_16x16x64_i8(
                af[2], bf[nt], acc[2][nt], 0, 0, 0);
#pragma unroll
        for (int nt = 0; nt < 4; ++nt)
            acc[3][nt] = __builtin_amdgcn_mfma_i32_16x16x64_i8(
                af[3], bf[nt], acc[3][nt], 0, 0, 0);

        asm volatile("s_waitcnt lgkmcnt(2)" ::: "memory");
        __builtin_amdgcn_sched_barrier(0);
#pragma unroll
        for (int nt = 0; nt < 4; ++nt)
            acc[4][nt] = __builtin_amdgcn_mfma_i32_16x16x64_i8(
                af[4], bf[nt], acc[4][nt], 0, 0, 0);
#pragma unroll
        for (int nt = 0; nt < 4; ++nt)
            acc[5][nt] = __builtin_amdgcn_mfma_i32_16x16x64_i8(
                af[5], bf[nt], acc[5][nt], 0, 0, 0);

        asm volatile("s_waitcnt lgkmcnt(0)" ::: "memory");
        __builtin_amdgcn_sched_barrier(0);
        // staging issued AFTER the last lgkm wait: vmem ops never alias the
        // counted-lgkm ledger. Slot (kt+2)&3 free since tile kt-2; lands by
        // the vmcnt(4) at the END of tile kt+1 -> a full tile of slack.
        if (kt + 2 < NKT) {
#pragma unroll
            for (int h = 0; h < 4; ++h) stage1((kt + 2) & 3, (kt + 2) * TKB, h);
        }
#pragma unroll
        for (int nt = 0; nt < 4; ++nt)
            acc[6][nt] = __builtin_amdgcn_mfma_i32_16x16x64_i8(
                af[6], bf[nt], acc[6][nt], 0, 0, 0);
#pragma unroll
        for (int nt = 0; nt < 4; ++nt)
            acc[7][nt] = __builtin_amdgcn_mfma_i32_16x16x64_i8(
                af[7], bf[nt], acc[7][nt], 0, 0, 0);
        __builtin_amdgcn_s_setprio(0);

        // counted drain: next tile's 4 loads must land; keep the following
        // tile's 4 in flight. Never 0 until the last edge.
        if (kt + 2 < NKT)
            asm volatile("s_waitcnt vmcnt(4)" ::: "memory");
        else if (kt + 2 == NKT)
            asm volatile("s_waitcnt vmcnt(0)" ::: "memory");
        if (kt + 1 < NKT) __builtin_amdgcn_s_barrier();
    }

    // ---- epilogue: acc[mt][nt][v] = idot(j, i) with
    //   j = j0 + wr*128 + mt*16 + q*4 + v   (32 in-lane candidates per nt)
    //   i = i0 + wc*64  + nt*16 + m16
    f32x4 cj[8];
#pragma unroll
    for (int mt = 0; mt < 8; ++mt)   // broadcast loads, L2-resident 32 KB
        cj[mt] = *(const f32x4*)(cterm + j0 + wr * 128 + mt * 16 + q * 4);

    unsigned kv[4];
    const bool diag = (i0 == j0);    // 32 of 1024 blocks
    if (!diag) {
#pragma unroll
        for (int nt = 0; nt < 4; ++nt) {
            float mx = -3.4e38f;
#pragma unroll
            for (int mt = 0; mt < 8; ++mt)
#pragma unroll
                for (int v = 0; v < 4; ++v)
                    mx = fmaxf(mx, ISQ * (float)acc[mt][nt][v] + cj[mt][v]);
            kv[nt] = key32(mx);
        }
    } else {
#pragma unroll
        for (int nt = 0; nt < 4; ++nt) {
            // j==i  <=>  mt*16+v == dtarget (at most one of the 32)
            const int dtarget = wc * 64 + nt * 16 + m16 - wr * 128 - q * 4;
            float mx = -3.4e38f;
#pragma unroll
            for (int mt = 0; mt < 8; ++mt)
#pragma unroll
                for (int v = 0; v < 4; ++v) {
                    const float sc = ISQ * (float)acc[mt][nt][v] + cj[mt][v];
                    mx = (mt * 16 + v == dtarget) ? mx : fmaxf(mx, sc);
                }
            kv[nt] = key32(mx);
        }
    }

    // combine the 4 q-groups (same i, different j): masks 16, 32
#pragma unroll
    for (int nt = 0; nt < 4; ++nt) {
#pragma unroll
        for (int msk = 16; msk < 64; msk <<= 1) {
            const unsigned o = (unsigned)__shfl_xor((int)kv[nt], msk);
            kv[nt] = o > kv[nt] ? o : kv[nt];
        }
    }
    if (lane < 16) {   // q==0 lanes hold the reduced keys
#pragma unroll
        for (int nt = 0; nt < 4; ++nt)
            smx[wr][wc * 64 + nt * 16 + m16] = kv[nt];
    }
    __syncthreads();
    if (t < 256) {
        const unsigned k0 = smx[0][t];
        const unsigned k1 = smx[1][t];
        // distributed per-row max: 32 blocks contend per address (order-
        // independent -> deterministic), 8192 addresses total.
        atomicMax(&rowmax[i0 + t], k0 > k1 ? k0 : k1);
    }
}

// ---------------------------------------------------------------------------
// K3: single block - loss = mean(relu(rowconst[i] + score_max[i])).
// Reads 64 KB; deterministic fixed-order sums.
// ---------------------------------------------------------------------------
__global__ __launch_bounds__(1024) void k_final(
    const unsigned* __restrict__ rowmax,
    const float* __restrict__ rowconst,
    float* __restrict__ out)
{
    __shared__ float smf[16];
    float s = 0.f;
    for (int k = threadIdx.x; k < Bn; k += 1024)
        s += fmaxf(rowconst[k] + unkey32(rowmax[k]), 0.f);
#pragma unroll
    for (int msk = 1; msk < 64; msk <<= 1) s += __shfl_xor(s, msk);
    if ((threadIdx.x & 63) == 0) smf[threadIdx.x >> 6] = s;
    __syncthreads();
    if (threadIdx.x == 0) {
        float tot = 0.f;
#pragma unroll
        for (int w = 0; w < 16; ++w) tot += smf[w];
        out[0] = tot * (1.0f / Bn);
    }
}

extern "C" void kernel_launch(void* const* d_in, const int* in_sizes, int n_in,
                              void* d_out, int out_size, void* d_ws, size_t ws_size,
                              hipStream_t stream)
{
    const float* x = (const float*)d_in[0];
    char* ws = (char*)d_ws;
    // workspace layout (bytes):
    uint8_t*  a_i8     = (uint8_t*)(ws + 0);         // 4 MB
    uint8_t*  p_i8     = (uint8_t*)(ws + 4194304);   // 4 MB
    float*    cterm    = (float*)(ws + 8388608);     // 32 KB
    float*    rowconst = (float*)(ws + 8421376);     // 32 KB
    unsigned* rowmax   = (unsigned*)(ws + 8454144);  // 32 KB (total ~8.5 MB)
    float*    out      = (float*)d_out;

    k_normalize<<<2048, 256, 0, stream>>>(x, a_i8, p_i8, cterm, rowconst, rowmax);
    k_gemm_argmax<<<dim3(Bn / 256, Bn / 256), 512, 0, stream>>>(
        a_i8, p_i8, cterm, rowmax);
    k_final<<<1, 1024, 0, stream>>>(rowmax, rowconst, out);
}